// Round 2
// baseline (1142.520 us; speedup 1.0000x reference)
//
#include <hip/hip_runtime.h>
#include <math.h>

// Problem constants (from the JAX reference)
#define NB 8            // batch
#define JJ 421          // J = 5*81 + 16
#define HDCN 256        // HDC
#define PP (JJ*HDCN)    // 107776 pixels per (batch,channel) plane
#define NCAH 32
#define STEPS 20

__device__ __forceinline__ float wave_reduce_sum(float v) {
#pragma unroll
    for (int off = 32; off > 0; off >>= 1) v += __shfl_down(v, off);
    return v;
}

// ---------------------------------------------------------------------------
// k_prep: s[b] = sum_i data[b,i]  where data = concat(data_input, structure, pe)
// ---------------------------------------------------------------------------
__global__ __launch_bounds__(128) void k_prep(
    const float* __restrict__ din,   // [8,36,9] = 324/batch
    const float* __restrict__ stin,  // [8,9,9]  = 81/batch
    const float* __restrict__ m_in,  // [8]
    const float* __restrict__ m_out, // [8]
    float* __restrict__ sbuf)        // [8] out
{
    int b = blockIdx.x, t = threadIdx.x;
    float acc = 0.f;
    for (int k = t; k < 324; k += 128) acc += din[b * 324 + k];
    for (int k = t; k < 81;  k += 128) acc += stin[b * 81 + k];
    if (t < 16) {
        int i = t;
        float pos_in  = m_in[b]  * 0.01f;   // / MAX_T(=100)
        float pos_out = m_out[b] * 0.01f;
        float div = powf(10000.0f, (float)(2 * (i / 2)) / 16.0f);
        float ai = pos_in / div, ao = pos_out / div;
        float v = ((i & 1) == 0) ? 0.5f * (sinf(ai) + cosf(ai))
                                 : 0.5f * (cosf(ai) + sinf(ao));
        acc += v;
    }
    __shared__ float part[2];
    float w = wave_reduce_sum(acc);
    if ((t & 63) == 0) part[t >> 6] = w;
    __syncthreads();
    if (t == 0) sbuf[b] = part[0] + part[1];
}

// ---------------------------------------------------------------------------
// k_x0: x0[b,o,jd] = tanh( A[o,jd] - 2p*B[o,jd] + p^2*C[o] + cb[o] ),
//   p = s[b]*hdc[b,jd];  A=sum_r w[o,r]*rbf^2, B=sum_r w[o,r]*rbf, C=sum_r w[o,r]
// One thread per pixel jd; the r-reduction is shared across all 8 batches.
// ---------------------------------------------------------------------------
__global__ __launch_bounds__(256) void k_x0(
    const float* __restrict__ rbf,   // [64,421,256]
    const float* __restrict__ hdc,   // [8,421,256]
    const float* __restrict__ cw,    // [5,64]
    const float* __restrict__ cb,    // [5]
    const float* __restrict__ sbuf,  // [8]
    float* __restrict__ x0)          // [8,5,421,256]
{
    __shared__ float wl[320];
    __shared__ float Cw[5];
    __shared__ float sb[8];
    __shared__ float cbs[5];
    int t = threadIdx.x;
    for (int k = t; k < 320; k += 256) wl[k] = cw[k];   // FIX: 320 > blockDim
    if (t < 8)   sb[t] = sbuf[t];
    if (t < 5)   cbs[t] = cb[t];
    __syncthreads();
    if (t < 5) { float c = 0.f; for (int r = 0; r < 64; ++r) c += wl[t * 64 + r]; Cw[t] = c; }
    __syncthreads();

    int jd = blockIdx.x * 256 + t;
    float A[5]  = {0, 0, 0, 0, 0};
    float Bv[5] = {0, 0, 0, 0, 0};
    for (int r = 0; r < 64; ++r) {
        float v  = rbf[(size_t)r * PP + jd];
        float v2 = v * v;
#pragma unroll
        for (int o = 0; o < 5; ++o) {
            float w = wl[o * 64 + r];
            A[o]  = fmaf(w, v2, A[o]);
            Bv[o] = fmaf(w, v,  Bv[o]);
        }
    }
#pragma unroll
    for (int b = 0; b < 8; ++b) {
        float p  = sb[b] * hdc[(size_t)b * PP + jd];
        float p2 = p * p;
#pragma unroll
        for (int o = 0; o < 5; ++o) {
            float val = A[o] - 2.f * p * Bv[o] + p2 * Cw[o] + cbs[o];
            x0[(size_t)(b * 5 + o) * PP + jd] = tanhf(val);
        }
    }
}

// ---------------------------------------------------------------------------
// k_nca: one NCA step.  h = relu(conv3x3_{5->32}(x)+b1); x += W2@h + b2
// Block = one (batch, j) row, 256 threads = the HDC dimension.
// batch = blockIdx&7 (XCD affinity: per-batch x is 2.15MB -> fits per-XCD L2).
// ---------------------------------------------------------------------------
__global__ __launch_bounds__(256) void k_nca(
    const float* __restrict__ xin,   // [8,5,421,256]
    float* __restrict__ xout,        // [8,5,421,256]
    const float* __restrict__ w1,    // [32,5,3,3]
    const float* __restrict__ b1,    // [32]
    const float* __restrict__ w2,    // [5,32]
    const float* __restrict__ b2)    // [5]
{
    __shared__ float xs[5][3][HDCN + 2];  // input tile with d-halo
    __shared__ float w1s[45 * 32];        // [c*9+tap][oc] for b128-friendly oc reads
    __shared__ float w2s[5 * 32];
    __shared__ float b1s[32];
    __shared__ float b2s[5];

    int t = threadIdx.x;
    int b = blockIdx.x & 7;
    int j = blockIdx.x >> 3;

    // weights -> LDS (reordered w1)
    for (int k = t; k < 1440; k += 256) {
        int oc = k / 45, rem = k % 45;       // w1 flat = oc*45 + (c*9+tap)
        w1s[rem * 32 + oc] = w1[k];
    }
    if (t < 160) w2s[t] = w2[t];
    if (t < 32)  b1s[t] = b1[t];
    if (t < 5)   b2s[t] = b2[t];

    const float* xb = xin + (size_t)b * 5 * PP;
#pragma unroll
    for (int c = 0; c < 5; ++c) {
#pragma unroll
        for (int r = 0; r < 3; ++r) {
            int jj = j + r - 1;
            float v = (jj >= 0 && jj < JJ) ? xb[(size_t)(c * JJ + jj) * HDCN + t] : 0.f;
            xs[c][r][t + 1] = v;
        }
    }
    if (t < 2) {
#pragma unroll
        for (int c = 0; c < 5; ++c)
#pragma unroll
            for (int r = 0; r < 3; ++r)
                xs[c][r][t * (HDCN + 1)] = 0.f;   // d-halo is always zero padding
    }
    __syncthreads();

    float h[NCAH];
#pragma unroll
    for (int oc = 0; oc < NCAH; ++oc) h[oc] = b1s[oc];

    for (int c = 0; c < 5; ++c) {
#pragma unroll
        for (int tap = 0; tap < 9; ++tap) {
            int dj = tap / 3, dd = tap % 3;
            float xv = xs[c][dj][t + dd];
            const float* wp = &w1s[(c * 9 + tap) * 32];
#pragma unroll
            for (int oc = 0; oc < NCAH; ++oc) h[oc] = fmaf(wp[oc], xv, h[oc]);
        }
    }
#pragma unroll
    for (int oc = 0; oc < NCAH; ++oc) h[oc] = fmaxf(h[oc], 0.f);

#pragma unroll
    for (int o = 0; o < 5; ++o) {
        float dx = b2s[o];
#pragma unroll
        for (int oc = 0; oc < NCAH; ++oc) dx = fmaf(w2s[o * 32 + oc], h[oc], dx);
        size_t idx = (size_t)(b * 5 + o) * PP + (size_t)j * HDCN + t;
        xout[idx] = xin[idx] + dx;
    }
}

// ---------------------------------------------------------------------------
// k_mean: m[bc,j] = mean_d tanh(x[bc,j,d]);  bc = b*5+c
// ---------------------------------------------------------------------------
__global__ __launch_bounds__(256) void k_mean(
    const float* __restrict__ x,     // [40,421,256]
    float* __restrict__ m)           // [40,421]
{
    int idx = blockIdx.x;            // 0 .. 40*421-1
    int t = threadIdx.x;
    float v = tanhf(x[(size_t)idx * HDCN + t]);
    __shared__ float part[4];
    float w = wave_reduce_sum(v);
    if ((t & 63) == 0) part[t >> 6] = w;
    __syncthreads();
    if (t == 0) m[idx] = (part[0] + part[1] + part[2] + part[3]) * (1.0f / 256.0f);
}

// ---------------------------------------------------------------------------
// k_out: adaptive pool J=421 -> 81, write outputs as concat(r,g,b,a,s)
// out[c*648 + b*81 + o]
// ---------------------------------------------------------------------------
__global__ __launch_bounds__(256) void k_out(
    const float* __restrict__ m,     // [40,421]
    float* __restrict__ out)         // [3240]
{
    int idx = blockIdx.x * 256 + threadIdx.x;
    if (idx >= 5 * NB * 81) return;
    int c = idx / (NB * 81);
    int rem = idx % (NB * 81);
    int b = rem / 81;
    int o = rem % 81;
    int s_ = (o * JJ) / 81;
    int e_ = ((o + 1) * JJ + 80) / 81;   // ceil
    float acc = 0.f;
    for (int jj = s_; jj < e_; ++jj) acc += m[(b * 5 + c) * JJ + jj];
    out[idx] = acc / (float)(e_ - s_);
}

// ---------------------------------------------------------------------------
extern "C" void kernel_launch(void* const* d_in, const int* in_sizes, int n_in,
                              void* d_out, int out_size, void* d_ws, size_t ws_size,
                              hipStream_t stream) {
    const float* data_in  = (const float*)d_in[0];
    const float* struc_in = (const float*)d_in[1];
    const float* meta_in  = (const float*)d_in[2];
    const float* meta_out = (const float*)d_in[3];
    const float* rbf      = (const float*)d_in[4];
    const float* hdc      = (const float*)d_in[5];
    const float* cw       = (const float*)d_in[6];
    const float* cb       = (const float*)d_in[7];
    const float* w1       = (const float*)d_in[8];
    const float* b1       = (const float*)d_in[9];
    const float* w2       = (const float*)d_in[10];
    const float* b2       = (const float*)d_in[11];
    float* out = (float*)d_out;

    float* ws   = (float*)d_ws;
    float* sbuf = ws;                       // 8 floats
    float* mbuf = ws + 64;                  // 40*421 = 16840 floats
    float* xA   = ws + 32768;               // [8,5,421,256]
    float* xB   = xA + (size_t)NB * 5 * PP; // second buffer

    k_prep<<<NB, 128, 0, stream>>>(data_in, struc_in, meta_in, meta_out, sbuf);
    k_x0<<<JJ, 256, 0, stream>>>(rbf, hdc, cw, cb, sbuf, xA);

    for (int step = 0; step < STEPS; ++step) {
        const float* xi = (step & 1) ? xB : xA;
        float*       xo = (step & 1) ? xA : xB;
        k_nca<<<NB * JJ, 256, 0, stream>>>(xi, xo, w1, b1, w2, b2);
    }
    // STEPS=20 is even -> final state is in xA
    k_mean<<<NB * 5 * JJ, 256, 0, stream>>>(xA, mbuf);
    k_out<<<(5 * NB * 81 + 255) / 256, 256, 0, stream>>>(mbuf, out);
}